// Round 17
// baseline (309.845 us; speedup 1.0000x reference)
//
#include <hip/hip_runtime.h>
#include <math.h>

#define N_NODES 4096

typedef unsigned short u16;
typedef unsigned int u32;

typedef __attribute__((ext_vector_type(8))) short bfrag;   // 8 bf16 = 4 VGPR
typedef __attribute__((ext_vector_type(4))) float f4;

__device__ __forceinline__ u16 f2bf(float x) {
    union { float f; u32 u; } v; v.f = x;
    u32 r = (v.u + 0x7FFFu + ((v.u >> 16) & 1u)) >> 16;   // RNE
    return (u16)r;
}
__device__ __forceinline__ float bf2f(u16 b) {
    union { float f; u32 u; } v; v.u = ((u32)b) << 16; return v.f;
}
__device__ __forceinline__ u32 cvtpk(float a, float b) {   // lo16=bf16(a), hi16=bf16(b)
    u32 r;
    asm("v_cvt_pk_bf16_f32 %0, %1, %2" : "=v"(r) : "v"(a), "v"(b));
    return r;
}
__device__ __forceinline__ float u2f(u32 u) {
    union { u32 u; float f; } v; v.u = u; return v.f;
}
__device__ __forceinline__ float fexp2(float x) {          // 2^x via v_exp_f32
    float r;
    asm("v_exp_f32 %0, %1" : "=v"(r) : "v"(x));
    return r;
}

#define LOG2E 1.4426950408889634f

// ---------------------------------------------------------------------------
// wprep: Wcat[k][col] as bf16 hi/mid/lo in B^T layout [col][576], swizzled.
// ---------------------------------------------------------------------------
__global__ __launch_bounds__(256) void wprep_kernel(
    const float* __restrict__ w1, const float* __restrict__ w2,
    const float* __restrict__ w3,
    u16* __restrict__ w_hi, u16* __restrict__ w_mid, u16* __restrict__ w_lo)
{
    int idx = blockIdx.x * 256 + threadIdx.x;
    if (idx >= 192 * 576) return;
    int col = idx / 576, k = idx % 576;
    int conv = col >> 6, o = col & 63;
    int kk = k / 192, c = k % 192;
    const float* w = (conv == 0) ? w1 : (conv == 1 ? w2 : w3);
    float v = w[(o * 192 + c) * 3 + kk];
    u16 h = f2bf(v);   float r1 = v - bf2f(h);
    u16 m = f2bf(r1);  float r2 = r1 - bf2f(m);
    u16 lo = f2bf(r2);
    int kc = k >> 6, rem = k & 63, j = rem >> 3, e = rem & 7;
    int pos = col * 576 + kc * 64 + ((j ^ (col & 7)) << 3) + e;
    w_hi[pos] = h;
    w_mid[pos] = m;
    w_lo[pos] = lo;
}

// ---------------------------------------------------------------------------
// timeblock_mfma (r6, passing): 3-way-split bf16 MFMA GEMM. grid (64,3).
// ---------------------------------------------------------------------------
__global__ __launch_bounds__(512) void timeblock_mfma_kernel(
    const float* __restrict__ flow,
    const u16* __restrict__ w_hi, const u16* __restrict__ w_mid,
    const u16* __restrict__ w_lo,
    const float* __restrict__ b1, const float* __restrict__ b2,
    const float* __restrict__ b3, float* __restrict__ x1)
{
    __shared__ __align__(16) u16 As[3][128 * 64];
    __shared__ __align__(16) u16 Bs[3][192 * 64];

    const int tid = threadIdx.x;
    const int wv = tid >> 6, l = tid & 63;
    const int ln15 = l & 15, ln16 = l >> 4;
    const int wr = wv >> 1, wc = wv & 1;
    const int nodebase = blockIdx.x * 128;
    const int t = blockIdx.y;

    f4 acc[2][6];
#pragma unroll
    for (int rq = 0; rq < 2; ++rq)
#pragma unroll
        for (int nt = 0; nt < 6; ++nt) {
            acc[rq][nt][0] = 0.f; acc[rq][nt][1] = 0.f;
            acc[rq][nt][2] = 0.f; acc[rq][nt][3] = 0.f;
        }

    for (int kc = 0; kc < 9; ++kc) {
        __syncthreads();

#pragma unroll
        for (int u = tid; u < 1024; u += 512) {
            int r = u >> 3, j = u & 7;
            const float* srcp = flow + (size_t)(nodebase + r) * 960 + t * 192 + kc * 64 + j * 8;
            float4 f0 = *(const float4*)srcp;
            float4 f1 = *(const float4*)(srcp + 4);
            float fv[8] = { f0.x, f0.y, f0.z, f0.w, f1.x, f1.y, f1.z, f1.w };
            union { uint4 q; u16 a[8]; } uh, um, ul;
#pragma unroll
            for (int e = 0; e < 8; ++e) {
                u16 h = f2bf(fv[e]);   float r1 = fv[e] - bf2f(h);
                u16 m = f2bf(r1);      float r2 = r1 - bf2f(m);
                uh.a[e] = h; um.a[e] = m; ul.a[e] = f2bf(r2);
            }
            int pos = r * 64 + ((j ^ (r & 7)) << 3);
            *(uint4*)&As[0][pos] = uh.q;
            *(uint4*)&As[1][pos] = um.q;
            *(uint4*)&As[2][pos] = ul.q;
        }

#pragma unroll
        for (int arr = 0; arr < 3; ++arr) {
            const u16* wsrc = (arr == 0) ? w_hi : (arr == 1 ? w_mid : w_lo);
#pragma unroll
            for (int i = 0; i < 3; ++i) {
                int colg = wv * 24 + i * 8;
                const u16* srcp = wsrc + (size_t)(colg + (l >> 3)) * 576 + kc * 64 + (l & 7) * 8;
                u16* dstp = &Bs[arr][colg * 64];
                __builtin_amdgcn_global_load_lds(
                    (const __attribute__((address_space(1))) u32*)srcp,
                    (__attribute__((address_space(3))) u32*)dstp, 16, 0, 0);
            }
        }

        __syncthreads();

        bfrag af[2][3][2];
#pragma unroll
        for (int rq = 0; rq < 2; ++rq) {
            int arow = wr * 32 + rq * 16 + ln15;
#pragma unroll
            for (int ks = 0; ks < 2; ++ks) {
                int idx = arow * 64 + (((ks * 4 + ln16) ^ (arow & 7)) << 3);
                af[rq][0][ks] = *(const bfrag*)&As[0][idx];
                af[rq][1][ks] = *(const bfrag*)&As[1][idx];
                af[rq][2][ks] = *(const bfrag*)&As[2][idx];
            }
        }

#pragma unroll
        for (int cv = 0; cv < 3; ++cv) {
#pragma unroll
            for (int ntj = 0; ntj < 2; ++ntj) {
                int col = cv * 64 + wc * 32 + ntj * 16 + ln15;
                int nt = cv * 2 + ntj;
#pragma unroll
                for (int ks = 0; ks < 2; ++ks) {
                    int idx = col * 64 + (((ks * 4 + ln16) ^ (col & 7)) << 3);
                    bfrag bh = *(const bfrag*)&Bs[0][idx];
                    bfrag bm = *(const bfrag*)&Bs[1][idx];
                    bfrag bl = *(const bfrag*)&Bs[2][idx];
#pragma unroll
                    for (int rq = 0; rq < 2; ++rq) {
                        f4 a = acc[rq][nt];
                        a = __builtin_amdgcn_mfma_f32_16x16x32_bf16(af[rq][0][ks], bh, a, 0, 0, 0);
                        a = __builtin_amdgcn_mfma_f32_16x16x32_bf16(af[rq][0][ks], bm, a, 0, 0, 0);
                        a = __builtin_amdgcn_mfma_f32_16x16x32_bf16(af[rq][1][ks], bh, a, 0, 0, 0);
                        a = __builtin_amdgcn_mfma_f32_16x16x32_bf16(af[rq][0][ks], bl, a, 0, 0, 0);
                        a = __builtin_amdgcn_mfma_f32_16x16x32_bf16(af[rq][2][ks], bh, a, 0, 0, 0);
                        a = __builtin_amdgcn_mfma_f32_16x16x32_bf16(af[rq][1][ks], bm, a, 0, 0, 0);
                        acc[rq][nt] = a;
                    }
                }
            }
        }
    }

#pragma unroll
    for (int rq = 0; rq < 2; ++rq) {
#pragma unroll
        for (int ntj = 0; ntj < 2; ++ntj) {
            int o = wc * 32 + ntj * 16 + ln15;
            float bb1 = b1[o], bb2 = b2[o], bb3 = b3[o];
#pragma unroll
            for (int rg = 0; rg < 4; ++rg) {
                int node = nodebase + wr * 32 + rq * 16 + ln16 * 4 + rg;
                float c1 = acc[rq][0 * 2 + ntj][rg] + bb1;
                float c2 = acc[rq][1 * 2 + ntj][rg] + bb2;
                float c3 = acc[rq][2 * 2 + ntj][rg] + bb3;
                float sg = 1.0f / (1.0f + __expf(-c2));
                float v = c1 + sg + c3;
                x1[(size_t)node * 192 + t * 64 + o] = v > 0.f ? v : 0.f;
            }
        }
    }
}

// ---------------------------------------------------------------------------
// linear_mfma (r16, passing): 3-way-split bf16 MFMA linear, dual-layout out.
// ---------------------------------------------------------------------------
__global__ __launch_bounds__(512) void linear_mfma_kernel(
    const float* __restrict__ in, const float* __restrict__ W,
    u16* __restrict__ h_hi, u16* __restrict__ h_lo,
    u16* __restrict__ hTb_hi, u16* __restrict__ hTb_lo,
    int C, int H, int nwc)
{
    __shared__ __align__(16) u16 As[3][256 * 64];
    __shared__ __align__(16) u16 Bs[3][128 * 64];

    const int tid = threadIdx.x;
    const int wv = tid >> 6, l = tid & 63;
    const int ln15 = l & 15, ln16 = l >> 4;
    const int wr = wv / nwc, wc = wv - wr * nwc;
    const int rows = 256 / nwc;
    const int ncol = 64 * nwc;
    const int rowbase = blockIdx.x * rows;
    const int colbase = blockIdx.y * ncol;

    f4 acc[2][4];
#pragma unroll
    for (int rq = 0; rq < 2; ++rq)
#pragma unroll
        for (int nt = 0; nt < 4; ++nt) {
            acc[rq][nt][0] = 0.f; acc[rq][nt][1] = 0.f;
            acc[rq][nt][2] = 0.f; acc[rq][nt][3] = 0.f;
        }

    const int nchunks = C >> 6;
    for (int kc = 0; kc < nchunks; ++kc) {
        __syncthreads();

        for (int u = tid; u < rows * 8; u += 512) {
            int r = u >> 3, j = u & 7;
            const float* srcp = in + (size_t)(rowbase + r) * C + kc * 64 + j * 8;
            float4 f0 = *(const float4*)srcp;
            float4 f1 = *(const float4*)(srcp + 4);
            float fv[8] = { f0.x, f0.y, f0.z, f0.w, f1.x, f1.y, f1.z, f1.w };
            union { uint4 q; u16 a[8]; } uh, um, ul;
#pragma unroll
            for (int e = 0; e < 8; ++e) {
                u16 h = f2bf(fv[e]);   float r1 = fv[e] - bf2f(h);
                u16 m = f2bf(r1);      float r2 = r1 - bf2f(m);
                uh.a[e] = h; um.a[e] = m; ul.a[e] = f2bf(r2);
            }
            int pos = r * 64 + ((j ^ (r & 7)) << 3);
            *(uint4*)&As[0][pos] = uh.q;
            *(uint4*)&As[1][pos] = um.q;
            *(uint4*)&As[2][pos] = ul.q;
        }

        for (int u = tid; u < ncol * 8; u += 512) {
            int cdx = u >> 3, j = u & 7;
            const float* srcp = W + (size_t)(colbase + cdx) * C + kc * 64 + j * 8;
            float4 f0 = *(const float4*)srcp;
            float4 f1 = *(const float4*)(srcp + 4);
            float fv[8] = { f0.x, f0.y, f0.z, f0.w, f1.x, f1.y, f1.z, f1.w };
            union { uint4 q; u16 a[8]; } uh, um, ul;
#pragma unroll
            for (int e = 0; e < 8; ++e) {
                u16 h = f2bf(fv[e]);   float r1 = fv[e] - bf2f(h);
                u16 m = f2bf(r1);      float r2 = r1 - bf2f(m);
                uh.a[e] = h; um.a[e] = m; ul.a[e] = f2bf(r2);
            }
            int pos = cdx * 64 + ((j ^ (cdx & 7)) << 3);
            *(uint4*)&Bs[0][pos] = uh.q;
            *(uint4*)&Bs[1][pos] = um.q;
            *(uint4*)&Bs[2][pos] = ul.q;
        }

        __syncthreads();

        bfrag af[2][3][2];
#pragma unroll
        for (int rq = 0; rq < 2; ++rq) {
            int arow = wr * 32 + rq * 16 + ln15;
#pragma unroll
            for (int ks = 0; ks < 2; ++ks) {
                int idx = arow * 64 + (((ks * 4 + ln16) ^ (arow & 7)) << 3);
                af[rq][0][ks] = *(const bfrag*)&As[0][idx];
                af[rq][1][ks] = *(const bfrag*)&As[1][idx];
                af[rq][2][ks] = *(const bfrag*)&As[2][idx];
            }
        }

#pragma unroll
        for (int nt = 0; nt < 4; ++nt) {
            int bcol = wc * 64 + nt * 16 + ln15;
#pragma unroll
            for (int ks = 0; ks < 2; ++ks) {
                int idx = bcol * 64 + (((ks * 4 + ln16) ^ (bcol & 7)) << 3);
                bfrag bh = *(const bfrag*)&Bs[0][idx];
                bfrag bm = *(const bfrag*)&Bs[1][idx];
                bfrag bl = *(const bfrag*)&Bs[2][idx];
#pragma unroll
                for (int rq = 0; rq < 2; ++rq) {
                    f4 a = acc[rq][nt];
                    a = __builtin_amdgcn_mfma_f32_16x16x32_bf16(af[rq][0][ks], bh, a, 0, 0, 0);
                    a = __builtin_amdgcn_mfma_f32_16x16x32_bf16(af[rq][0][ks], bm, a, 0, 0, 0);
                    a = __builtin_amdgcn_mfma_f32_16x16x32_bf16(af[rq][1][ks], bh, a, 0, 0, 0);
                    a = __builtin_amdgcn_mfma_f32_16x16x32_bf16(af[rq][0][ks], bl, a, 0, 0, 0);
                    a = __builtin_amdgcn_mfma_f32_16x16x32_bf16(af[rq][2][ks], bh, a, 0, 0, 0);
                    a = __builtin_amdgcn_mfma_f32_16x16x32_bf16(af[rq][1][ks], bm, a, 0, 0, 0);
                    acc[rq][nt] = a;
                }
            }
        }
    }

#pragma unroll
    for (int rq = 0; rq < 2; ++rq) {
#pragma unroll
        for (int nt = 0; nt < 4; ++nt) {
            int col = colbase + wc * 64 + nt * 16 + ln15;
            int g = col >> 6, d = col & 63;
            u16 hi4[4], lo4[4];
#pragma unroll
            for (int rg = 0; rg < 4; ++rg) {
                float a = acc[rq][nt][rg];
                u16 h = f2bf(a);
                hi4[rg] = h;
                lo4[rg] = f2bf(a - bf2f(h));
            }
            int row0 = rowbase + wr * 32 + rq * 16 + ln16 * 4;
            int b = row0 >> 12;
            int n0 = row0 & 4095;
            size_t mapb = (size_t)(b * H + g) * (4096 * 64);
#pragma unroll
            for (int rg = 0; rg < 4; ++rg) {
                h_hi[mapb + (size_t)(n0 + rg) * 64 + d] = hi4[rg];
                h_lo[mapb + (size_t)(n0 + rg) * 64 + d] = lo4[rg];
            }
            size_t tb = mapb + (size_t)(n0 >> 6) * 4096;
            ushort4 vh = { hi4[0], hi4[1], hi4[2], hi4[3] };
            ushort4 vl = { lo4[0], lo4[1], lo4[2], lo4[3] };
            *(ushort4*)&hTb_hi[tb + (size_t)d * 64 + (n0 & 63)] = vh;
            *(ushort4*)&hTb_lo[tb + (size_t)d * 64 + (n0 & 63)] = vl;
        }
    }
}

// ---------------------------------------------------------------------------
// flash_mfma (r15, kept for flash4): K dbuf + V single, 48 KB LDS.
// ---------------------------------------------------------------------------
__global__ __launch_bounds__(256) void flash_mfma_kernel(
    const u16* __restrict__ h_hi, const u16* __restrict__ h_lo,
    const u16* __restrict__ hTb_hi, const u16* __restrict__ hTb_lo,
    const float* __restrict__ graph, const float* __restrict__ bias,
    float* __restrict__ out, int H, int rstride,
    int ntiles, int nch, int mode, float* __restrict__ pO, float* __restrict__ pml)
{
    __shared__ __align__(16) u16 Ks[2][2][4096];
    __shared__ __align__(16) u16 Vs[2][4096];

    const int tid = threadIdx.x;
    const int wv = tid >> 6;
    const int l = tid & 63;
    const int ln15 = l & 15, ln16 = l >> 4;
    const int bx = blockIdx.y;
    const int by = bx / nch;
    const int chunk = bx - by * nch;
    const int t0 = chunk * ntiles;
    const int bb = by / H, head = by - bb * H;
    const size_t mapb = (size_t)by * (4096 * 64);
    const int rowbase = blockIdx.x * 64;

    const int arow = rowbase + wv * 16 + ln15;
    bfrag ahi[2], alo[2];
#pragma unroll
    for (int ks = 0; ks < 2; ++ks) {
        ahi[ks] = *(const bfrag*)(h_hi + mapb + (size_t)arow * 64 + ks * 32 + ln16 * 8);
        alo[ks] = *(const bfrag*)(h_lo + mapb + (size_t)arow * 64 + ks * 32 + ln16 * 8);
    }

    const u16* gA = (wv == 0 ? h_hi : wv == 1 ? h_lo : wv == 2 ? hTb_hi : hTb_lo) + mapb;
    const int lrow = l >> 3;
    const int stoff = lrow * 64 + (((l & 7) ^ lrow) << 3);

#define STAGE_K(T, BUF)                                                        \
    if (wv < 2) {                                                              \
        const u16* srcp = gA + (size_t)(T) * 4096 + stoff;                     \
        u16* dstp = &Ks[BUF][wv][0];                                           \
        _Pragma("unroll")                                                      \
        for (int i_ = 0; i_ < 8; ++i_)                                         \
            __builtin_amdgcn_global_load_lds(                                  \
                (const __attribute__((address_space(1))) u32*)(srcp + i_ * 512), \
                (__attribute__((address_space(3))) u32*)(dstp + i_ * 512),     \
                16, 0, 0);                                                     \
    }
#define STAGE_V(T)                                                             \
    if (wv >= 2) {                                                             \
        const u16* srcp = gA + (size_t)(T) * 4096 + stoff;                     \
        u16* dstp = &Vs[wv - 2][0];                                            \
        _Pragma("unroll")                                                      \
        for (int i_ = 0; i_ < 8; ++i_)                                         \
            __builtin_amdgcn_global_load_lds(                                  \
                (const __attribute__((address_space(1))) u32*)(srcp + i_ * 512), \
                (__attribute__((address_space(3))) u32*)(dstp + i_ * 512),     \
                16, 0, 0);                                                     \
    }

    const float* grow = graph + (size_t)(rowbase + wv * 16 + ln15) * 4096 + ln16 * 4;

    float m_ = -3.0e38f, l_ = 0.f;
    f4 acco[4];
#pragma unroll
    for (int i = 0; i < 4; ++i) {
        acco[i][0] = 0.f; acco[i][1] = 0.f; acco[i][2] = 0.f; acco[i][3] = 0.f;
    }

    STAGE_K(t0, 0);
    float4 grC[4], grN[4];
#pragma unroll
    for (int cb = 0; cb < 4; ++cb)
        grC[cb] = *(const float4*)(grow + (size_t)t0 * 64 + cb * 16);

    const int srcA = ln15 + ((((ln16 << 1)) & 3) << 4);
    const int srcB = ln15 + ((((ln16 << 1) + 1) & 3) << 4);
    const bool hi2 = (ln16 & 2) != 0;

    for (int tt = 0; tt < ntiles; ++tt) {
        const int t = t0 + tt;
        const int cur = tt & 1;

        __syncthreads();

        STAGE_V(t);
        if (tt + 1 < ntiles) {
            STAGE_K(t + 1, cur ^ 1);
#pragma unroll
            for (int cb = 0; cb < 4; ++cb)
                grN[cb] = *(const float4*)(grow + (size_t)(t + 1) * 64 + cb * 16);
        }

        __builtin_amdgcn_s_setprio(1);
        f4 accs[4];
#pragma unroll
        for (int cb = 0; cb < 4; ++cb) {
            f4 a; a[0] = 0.f; a[1] = 0.f; a[2] = 0.f; a[3] = 0.f;
#pragma unroll
            for (int ks = 0; ks < 2; ++ks) {
                int c = cb * 16 + ln15;
                int idx = c * 64 + (((ks * 4 + ln16) * 8) ^ ((c & 7) << 3));
                bfrag bhi = *(const bfrag*)&Ks[cur][0][idx];
                bfrag blo = *(const bfrag*)&Ks[cur][1][idx];
                a = __builtin_amdgcn_mfma_f32_16x16x32_bf16(bhi, ahi[ks], a, 0, 0, 0);
                a = __builtin_amdgcn_mfma_f32_16x16x32_bf16(bhi, alo[ks], a, 0, 0, 0);
                a = __builtin_amdgcn_mfma_f32_16x16x32_bf16(blo, ahi[ks], a, 0, 0, 0);
            }
            accs[cb] = a;
        }
        __builtin_amdgcn_s_setprio(0);

        float p[4][4];
#pragma unroll
        for (int cb = 0; cb < 4; ++cb) {
            p[cb][0] = accs[cb][0] + fmaf(grC[cb].x, 1e16f, -1e16f);
            p[cb][1] = accs[cb][1] + fmaf(grC[cb].y, 1e16f, -1e16f);
            p[cb][2] = accs[cb][2] + fmaf(grC[cb].z, 1e16f, -1e16f);
            p[cb][3] = accs[cb][3] + fmaf(grC[cb].w, 1e16f, -1e16f);
        }

        float tm = fmaxf(fmaxf(p[0][0], p[0][1]), fmaxf(p[0][2], p[0][3]));
#pragma unroll
        for (int cb = 1; cb < 4; ++cb)
            tm = fmaxf(tm, fmaxf(fmaxf(p[cb][0], p[cb][1]), fmaxf(p[cb][2], p[cb][3])));
        tm = fmaxf(tm, __shfl_xor(tm, 16));
        tm = fmaxf(tm, __shfl_xor(tm, 32));

        const bool anyup = __any(tm > m_);
        float mn, corr;
        if (anyup) {
            mn = fmaxf(m_, tm);
            corr = fexp2((m_ - mn) * LOG2E);
        } else {
            mn = m_;
            corr = 1.0f;
        }
        const float c0 = -mn * LOG2E;

        float rs = 0.f;
#pragma unroll
        for (int cb = 0; cb < 4; ++cb) {
            p[cb][0] = fexp2(fmaf(p[cb][0], LOG2E, c0));
            p[cb][1] = fexp2(fmaf(p[cb][1], LOG2E, c0));
            p[cb][2] = fexp2(fmaf(p[cb][2], LOG2E, c0));
            p[cb][3] = fexp2(fmaf(p[cb][3], LOG2E, c0));
            rs += (p[cb][0] + p[cb][1]) + (p[cb][2] + p[cb][3]);
        }
        rs += __shfl_xor(rs, 16);
        rs += __shfl_xor(rs, 32);
        l_ = l_ * corr + rs;
        m_ = mn;

        if (anyup) {
            float corr4[4];
#pragma unroll
            for (int rg = 0; rg < 4; ++rg)
                corr4[rg] = __shfl(corr, ln16 * 4 + rg);
#pragma unroll
            for (int nb = 0; nb < 4; ++nb) {
                acco[nb][0] *= corr4[0]; acco[nb][1] *= corr4[1];
                acco[nb][2] *= corr4[2]; acco[nb][3] *= corr4[3];
            }
        }

        u32 Uh[4][2], Ul[4][2];
#pragma unroll
        for (int cb = 0; cb < 4; ++cb) {
            u32 uh0 = cvtpk(p[cb][0], p[cb][1]);
            u32 uh1 = cvtpk(p[cb][2], p[cb][3]);
            float h0 = u2f(uh0 << 16), h1 = u2f(uh0 & 0xffff0000u);
            float h2 = u2f(uh1 << 16), h3 = u2f(uh1 & 0xffff0000u);
            Uh[cb][0] = uh0; Uh[cb][1] = uh1;
            Ul[cb][0] = cvtpk(p[cb][0] - h0, p[cb][1] - h1);
            Ul[cb][1] = cvtpk(p[cb][2] - h2, p[cb][3] - h3);
        }

        bfrag pfh[2], pfl[2];
#pragma unroll
        for (int ks = 0; ks < 2; ++ks) {
            u32 w0a = (u32)__shfl((int)Uh[2 * ks + 0][0], srcA);
            u32 w0b = (u32)__shfl((int)Uh[2 * ks + 1][0], srcA);
            u32 w1a = (u32)__shfl((int)Uh[2 * ks + 0][1], srcA);
            u32 w1b = (u32)__shfl((int)Uh[2 * ks + 1][1], srcA);
            u32 w2a = (u32)__shfl((int)Uh[2 * ks + 0][0], srcB);
            u32 w2b = (u32)__shfl((int)Uh[2 * ks + 1][0], srcB);
            u32 w3a = (u32)__shfl((int)Uh[2 * ks + 0][1], srcB);
            u32 w3b = (u32)__shfl((int)Uh[2 * ks + 1][1], srcB);
            union { uint4 q; bfrag f; } ch;
            ch.q.x = hi2 ? w0b : w0a; ch.q.y = hi2 ? w1b : w1a;
            ch.q.z = hi2 ? w2b : w2a; ch.q.w = hi2 ? w3b : w3a;
            pfh[ks] = ch.f;

            u32 v0a = (u32)__shfl((int)Ul[2 * ks + 0][0], srcA);
            u32 v0b = (u32)__shfl((int)Ul[2 * ks + 1][0], srcA);
            u32 v1a = (u32)__shfl((int)Ul[2 * ks + 0][1], srcA);
            u32 v1b = (u32)__shfl((int)Ul[2 * ks + 1][1], srcA);
            u32 v2a = (u32)__shfl((int)Ul[2 * ks + 0][0], srcB);
            u32 v2b = (u32)__shfl((int)Ul[2 * ks + 1][0], srcB);
            u32 v3a = (u32)__shfl((int)Ul[2 * ks + 0][1], srcB);
            u32 v3b = (u32)__shfl((int)Ul[2 * ks + 1][1], srcB);
            union { uint4 q; bfrag f; } cl;
            cl.q.x = hi2 ? v0b : v0a; cl.q.y = hi2 ? v1b : v1a;
            cl.q.z = hi2 ? v2b : v2a; cl.q.w = hi2 ? v3b : v3a;
            pfl[ks] = cl.f;
        }

        __syncthreads();   // publish V(t)

        __builtin_amdgcn_s_setprio(1);
#pragma unroll
        for (int nb = 0; nb < 4; ++nb) {
#pragma unroll
            for (int ks = 0; ks < 2; ++ks) {
                int nr = nb * 16 + ln15;
                int idx = nr * 64 + (((ks * 4 + ln16) * 8) ^ ((nr & 7) << 3));
                bfrag vhi = *(const bfrag*)&Vs[0][idx];
                bfrag vlo = *(const bfrag*)&Vs[1][idx];
                acco[nb] = __builtin_amdgcn_mfma_f32_16x16x32_bf16(pfh[ks], vhi, acco[nb], 0, 0, 0);
                acco[nb] = __builtin_amdgcn_mfma_f32_16x16x32_bf16(pfh[ks], vlo, acco[nb], 0, 0, 0);
                acco[nb] = __builtin_amdgcn_mfma_f32_16x16x32_bf16(pfl[ks], vhi, acco[nb], 0, 0, 0);
            }
        }
        __builtin_amdgcn_s_setprio(0);

        if (tt + 1 < ntiles) {
#pragma unroll
            for (int cb = 0; cb < 4; ++cb)
                grC[cb] = grN[cb];
        }
    }
#undef STAGE_K
#undef STAGE_V

    if (mode == 0) {
        float l4[4];
#pragma unroll
        for (int rg = 0; rg < 4; ++rg)
            l4[rg] = __shfl(l_, ln16 * 4 + rg);

        const float* bv = bias + head * 64;
#pragma unroll
        for (int rg = 0; rg < 4; ++rg) {
            int row = rowbase + wv * 16 + ln16 * 4 + rg;
            float inv = 1.0f / l4[rg];
#pragma unroll
            for (int nb = 0; nb < 4; ++nb) {
                float v = acco[nb][rg] * inv + bv[nb * 16 + ln15];
                v = v > 0.f ? v : 0.01f * v;
                out[(size_t)(bb * N_NODES + row) * rstride + head * 64 + nb * 16 + ln15] = v;
            }
        }
    } else {
        int row = rowbase + wv * 16 + ln15;
        if (ln16 == 0) {
            size_t mi = (((size_t)(by * nch + chunk)) * 4096 + row) * 2;
            pml[mi] = m_;
            pml[mi + 1] = l_;
        }
#pragma unroll
        for (int rg = 0; rg < 4; ++rg) {
            int row2 = rowbase + wv * 16 + ln16 * 4 + rg;
            size_t ob = (((size_t)(by * nch + chunk)) * 4096 + row2) * 64;
#pragma unroll
            for (int nb = 0; nb < 4; ++nb)
                pO[ob + nb * 16 + ln15] = acco[nb][rg];
        }
    }
}

// ---------------------------------------------------------------------------
// flash1s (r17): 32 KB LDS (K AND V single-buffered) -> 1024 blocks all
// resident at 4/CU. K(t+1) staged after post-S barrier (hidden under
// softmax+PV); V(t) staged at tile top (hidden under S+softmax). 3 barriers.
// Always mode-1 (partial dump).
// ---------------------------------------------------------------------------
__global__ __launch_bounds__(256) void flash1s_kernel(
    const u16* __restrict__ h_hi, const u16* __restrict__ h_lo,
    const u16* __restrict__ hTb_hi, const u16* __restrict__ hTb_lo,
    const float* __restrict__ graph,
    int H, int ntiles, int nch, float* __restrict__ pO, float* __restrict__ pml)
{
    __shared__ __align__(16) u16 Ks[2][4096];      // K_hi,K_lo 16 KB single
    __shared__ __align__(16) u16 Vs[2][4096];      // V_hi,V_lo 16 KB single

    const int tid = threadIdx.x;
    const int wv = tid >> 6;
    const int l = tid & 63;
    const int ln15 = l & 15, ln16 = l >> 4;
    const int bx = blockIdx.y;        // by*nch + chunk
    const int by = bx / nch;
    const int chunk = bx - by * nch;
    const int t0 = chunk * ntiles;
    const size_t mapb = (size_t)by * (4096 * 64);
    const int rowbase = blockIdx.x * 64;

    const int arow = rowbase + wv * 16 + ln15;
    bfrag ahi[2], alo[2];
#pragma unroll
    for (int ks = 0; ks < 2; ++ks) {
        ahi[ks] = *(const bfrag*)(h_hi + mapb + (size_t)arow * 64 + ks * 32 + ln16 * 8);
        alo[ks] = *(const bfrag*)(h_lo + mapb + (size_t)arow * 64 + ks * 32 + ln16 * 8);
    }

    const u16* gA = (wv == 0 ? h_hi : wv == 1 ? h_lo : wv == 2 ? hTb_hi : hTb_lo) + mapb;
    const int lrow = l >> 3;
    const int stoff = lrow * 64 + (((l & 7) ^ lrow) << 3);

#define STAGE_K1(T)                                                            \
    if (wv < 2) {                                                              \
        const u16* srcp = gA + (size_t)(T) * 4096 + stoff;                     \
        u16* dstp = &Ks[wv][0];                                                \
        _Pragma("unroll")                                                      \
        for (int i_ = 0; i_ < 8; ++i_)                                         \
            __builtin_amdgcn_global_load_lds(                                  \
                (const __attribute__((address_space(1))) u32*)(srcp + i_ * 512), \
                (__attribute__((address_space(3))) u32*)(dstp + i_ * 512),     \
                16, 0, 0);                                                     \
    }
#define STAGE_V1(T)                                                            \
    if (wv >= 2) {                                                             \
        const u16* srcp = gA + (size_t)(T) * 4096 + stoff;                     \
        u16* dstp = &Vs[wv - 2][0];                                            \
        _Pragma("unroll")                                                      \
        for (int i_ = 0; i_ < 8; ++i_)                                         \
            __builtin_amdgcn_global_load_lds(                                  \
                (const __attribute__((address_space(1))) u32*)(srcp + i_ * 512), \
                (__attribute__((address_space(3))) u32*)(dstp + i_ * 512),     \
                16, 0, 0);                                                     \
    }

    const float* grow = graph + (size_t)(rowbase + wv * 16 + ln15) * 4096 + ln16 * 4;

    float m_ = -3.0e38f, l_ = 0.f;
    f4 acco[4];
#pragma unroll
    for (int i = 0; i < 4; ++i) {
        acco[i][0] = 0.f; acco[i][1] = 0.f; acco[i][2] = 0.f; acco[i][3] = 0.f;
    }

    STAGE_K1(t0);
    float4 grC[4], grN[4];
#pragma unroll
    for (int cb = 0; cb < 4; ++cb)
        grC[cb] = *(const float4*)(grow + (size_t)t0 * 64 + cb * 16);

    const int srcA = ln15 + ((((ln16 << 1)) & 3) << 4);
    const int srcB = ln15 + ((((ln16 << 1) + 1) & 3) << 4);
    const bool hi2 = (ln16 & 2) != 0;

    for (int tt = 0; tt < ntiles; ++tt) {
        const int t = t0 + tt;

        __syncthreads();   // publishes K(t) (staged prev iter / prologue); V buf free

        STAGE_V1(t);       // consumed after pre-PV barrier (~2k cyc away)

        // ---- S^T phase: reads Ks (single buffer) ----
        __builtin_amdgcn_s_setprio(1);
        f4 accs[4];
#pragma unroll
        for (int cb = 0; cb < 4; ++cb) {
            f4 a; a[0] = 0.f; a[1] = 0.f; a[2] = 0.f; a[3] = 0.f;
#pragma unroll
            for (int ks = 0; ks < 2; ++ks) {
                int c = cb * 16 + ln15;
                int idx = c * 64 + (((ks * 4 + ln16) * 8) ^ ((c & 7) << 3));
                bfrag bhi = *(const bfrag*)&Ks[0][idx];
                bfrag blo = *(const bfrag*)&Ks[1][idx];
                a = __builtin_amdgcn_mfma_f32_16x16x32_bf16(bhi, ahi[ks], a, 0, 0, 0);
                a = __builtin_amdgcn_mfma_f32_16x16x32_bf16(bhi, alo[ks], a, 0, 0, 0);
                a = __builtin_amdgcn_mfma_f32_16x16x32_bf16(blo, ahi[ks], a, 0, 0, 0);
            }
            accs[cb] = a;
        }
        __builtin_amdgcn_s_setprio(0);

        __syncthreads();   // all waves done reading K(t) -> safe to restage

        if (tt + 1 < ntiles) {
            STAGE_K1(t + 1);   // lands during softmax+PV (~3k cyc)
#pragma unroll
            for (int cb = 0; cb < 4; ++cb)
                grN[cb] = *(const float4*)(grow + (size_t)(t + 1) * 64 + cb * 16);
        }

        // ---- additive mask + online softmax ----
        float p[4][4];
#pragma unroll
        for (int cb = 0; cb < 4; ++cb) {
            p[cb][0] = accs[cb][0] + fmaf(grC[cb].x, 1e16f, -1e16f);
            p[cb][1] = accs[cb][1] + fmaf(grC[cb].y, 1e16f, -1e16f);
            p[cb][2] = accs[cb][2] + fmaf(grC[cb].z, 1e16f, -1e16f);
            p[cb][3] = accs[cb][3] + fmaf(grC[cb].w, 1e16f, -1e16f);
        }

        float tm = fmaxf(fmaxf(p[0][0], p[0][1]), fmaxf(p[0][2], p[0][3]));
#pragma unroll
        for (int cb = 1; cb < 4; ++cb)
            tm = fmaxf(tm, fmaxf(fmaxf(p[cb][0], p[cb][1]), fmaxf(p[cb][2], p[cb][3])));
        tm = fmaxf(tm, __shfl_xor(tm, 16));
        tm = fmaxf(tm, __shfl_xor(tm, 32));

        const bool anyup = __any(tm > m_);
        float mn, corr;
        if (anyup) {
            mn = fmaxf(m_, tm);
            corr = fexp2((m_ - mn) * LOG2E);
        } else {
            mn = m_;
            corr = 1.0f;
        }
        const float c0 = -mn * LOG2E;

        float rs = 0.f;
#pragma unroll
        for (int cb = 0; cb < 4; ++cb) {
            p[cb][0] = fexp2(fmaf(p[cb][0], LOG2E, c0));
            p[cb][1] = fexp2(fmaf(p[cb][1], LOG2E, c0));
            p[cb][2] = fexp2(fmaf(p[cb][2], LOG2E, c0));
            p[cb][3] = fexp2(fmaf(p[cb][3], LOG2E, c0));
            rs += (p[cb][0] + p[cb][1]) + (p[cb][2] + p[cb][3]);
        }
        rs += __shfl_xor(rs, 16);
        rs += __shfl_xor(rs, 32);
        l_ = l_ * corr + rs;
        m_ = mn;

        if (anyup) {
            float corr4[4];
#pragma unroll
            for (int rg = 0; rg < 4; ++rg)
                corr4[rg] = __shfl(corr, ln16 * 4 + rg);
#pragma unroll
            for (int nb = 0; nb < 4; ++nb) {
                acco[nb][0] *= corr4[0]; acco[nb][1] *= corr4[1];
                acco[nb][2] *= corr4[2]; acco[nb][3] *= corr4[3];
            }
        }

        u32 Uh[4][2], Ul[4][2];
#pragma unroll
        for (int cb = 0; cb < 4; ++cb) {
            u32 uh0 = cvtpk(p[cb][0], p[cb][1]);
            u32 uh1 = cvtpk(p[cb][2], p[cb][3]);
            float h0 = u2f(uh0 << 16), h1 = u2f(uh0 & 0xffff0000u);
            float h2 = u2f(uh1 << 16), h3 = u2f(uh1 & 0xffff0000u);
            Uh[cb][0] = uh0; Uh[cb][1] = uh1;
            Ul[cb][0] = cvtpk(p[cb][0] - h0, p[cb][1] - h1);
            Ul[cb][1] = cvtpk(p[cb][2] - h2, p[cb][3] - h3);
        }

        bfrag pfh[2], pfl[2];
#pragma unroll
        for (int ks = 0; ks < 2; ++ks) {
            u32 w0a = (u32)__shfl((int)Uh[2 * ks + 0][0], srcA);
            u32 w0b = (u32)__shfl((int)Uh[2 * ks + 1][0], srcA);
            u32 w1a = (u32)__shfl((int)Uh[2 * ks + 0][1], srcA);
            u32 w1b = (u32)__shfl((int)Uh[2 * ks + 1][1], srcA);
            u32 w2a = (u32)__shfl((int)Uh[2 * ks + 0][0], srcB);
            u32 w2b = (u32)__shfl((int)Uh[2 * ks + 1][0], srcB);
            u32 w3a = (u32)__shfl((int)Uh[2 * ks + 0][1], srcB);
            u32 w3b = (u32)__shfl((int)Uh[2 * ks + 1][1], srcB);
            union { uint4 q; bfrag f; } ch;
            ch.q.x = hi2 ? w0b : w0a; ch.q.y = hi2 ? w1b : w1a;
            ch.q.z = hi2 ? w2b : w2a; ch.q.w = hi2 ? w3b : w3a;
            pfh[ks] = ch.f;

            u32 v0a = (u32)__shfl((int)Ul[2 * ks + 0][0], srcA);
            u32 v0b = (u32)__shfl((int)Ul[2 * ks + 1][0], srcA);
            u32 v1a = (u32)__shfl((int)Ul[2 * ks + 0][1], srcA);
            u32 v1b = (u32)__shfl((int)Ul[2 * ks + 1][1], srcA);
            u32 v2a = (u32)__shfl((int)Ul[2 * ks + 0][0], srcB);
            u32 v2b = (u32)__shfl((int)Ul[2 * ks + 1][0], srcB);
            u32 v3a = (u32)__shfl((int)Ul[2 * ks + 0][1], srcB);
            u32 v3b = (u32)__shfl((int)Ul[2 * ks + 1][1], srcB);
            union { uint4 q; bfrag f; } cl;
            cl.q.x = hi2 ? v0b : v0a; cl.q.y = hi2 ? v1b : v1a;
            cl.q.z = hi2 ? v2b : v2a; cl.q.w = hi2 ? v3b : v3a;
            pfl[ks] = cl.f;
        }

        __syncthreads();   // publish V(t)

        __builtin_amdgcn_s_setprio(1);
#pragma unroll
        for (int nb = 0; nb < 4; ++nb) {
#pragma unroll
            for (int ks = 0; ks < 2; ++ks) {
                int nr = nb * 16 + ln15;
                int idx = nr * 64 + (((ks * 4 + ln16) * 8) ^ ((nr & 7) << 3));
                bfrag vhi = *(const bfrag*)&Vs[0][idx];
                bfrag vlo = *(const bfrag*)&Vs[1][idx];
                acco[nb] = __builtin_amdgcn_mfma_f32_16x16x32_bf16(pfh[ks], vhi, acco[nb], 0, 0, 0);
                acco[nb] = __builtin_amdgcn_mfma_f32_16x16x32_bf16(pfh[ks], vlo, acco[nb], 0, 0, 0);
                acco[nb] = __builtin_amdgcn_mfma_f32_16x16x32_bf16(pfl[ks], vhi, acco[nb], 0, 0, 0);
            }
        }
        __builtin_amdgcn_s_setprio(0);

        if (tt + 1 < ntiles) {
#pragma unroll
            for (int cb = 0; cb < 4; ++cb)
                grC[cb] = grN[cb];
        }
    }
#undef STAGE_K1
#undef STAGE_V1

    // partial dump
    int row = rowbase + wv * 16 + ln15;
    if (ln16 == 0) {
        size_t mi = (((size_t)(by * nch + chunk)) * 4096 + row) * 2;
        pml[mi] = m_;
        pml[mi + 1] = l_;
    }
#pragma unroll
    for (int rg = 0; rg < 4; ++rg) {
        int row2 = rowbase + wv * 16 + ln16 * 4 + rg;
        size_t ob = (((size_t)(by * nch + chunk)) * 4096 + row2) * 64;
#pragma unroll
        for (int nb = 0; nb < 4; ++nb)
            pO[ob + nb * 16 + ln15] = acco[nb][rg];
    }
}

// ---------------------------------------------------------------------------
// merge: combine nch column-chunk partials -> out = leaky(num/den + bias)
// ---------------------------------------------------------------------------
__global__ __launch_bounds__(256) void merge_kernel(
    const float* __restrict__ pO, const float* __restrict__ pml,
    const float* __restrict__ bias, float* __restrict__ out, int nch)
{
    int idx = blockIdx.x * 256 + threadIdx.x;   // 2*4096*64 total
    int feat = idx & 63;
    int row = (idx >> 6) & 4095;
    int map = idx >> 18;

    float M = -3.0e38f;
    for (int c = 0; c < nch; ++c) {
        size_t mi = (((size_t)map * nch + c) * 4096 + row) * 2;
        M = fmaxf(M, pml[mi]);
    }
    float den = 0.f, num = 0.f;
    for (int c = 0; c < nch; ++c) {
        size_t mi = (((size_t)map * nch + c) * 4096 + row) * 2;
        float e = __expf(pml[mi] - M);
        den += e * pml[mi + 1];
        num += e * pO[(((size_t)map * nch + c) * 4096 + row) * 64 + feat];
    }
    float v = num / den + bias[feat];
    v = v > 0.f ? v : 0.01f * v;
    out[((size_t)map * 4096 + row) * 64 + feat] = v;
}

// ---------------------------------------------------------------------------
extern "C" void kernel_launch(void* const* d_in, const int* in_sizes, int n_in,
                              void* d_out, int out_size, void* d_ws, size_t ws_size,
                              hipStream_t stream)
{
    const float* flow = (const float*)d_in[0];
    const float* graph = (const float*)d_in[1];
    const float* w1 = (const float*)d_in[2];
    const float* b1 = (const float*)d_in[3];
    const float* w2 = (const float*)d_in[4];
    const float* b2 = (const float*)d_in[5];
    const float* w3 = (const float*)d_in[6];
    const float* b3 = (const float*)d_in[7];
    const float* Wh = (const float*)d_in[8];
    const float* bh = (const float*)d_in[9];
    const float* Wo = (const float*)d_in[10];
    const float* bo = (const float*)d_in[11];

    char* ws = (char*)d_ws;
    u16* wc_hi  = (u16*)ws;                          // aliases h1 region
    u16* wc_mid = wc_hi + (size_t)192 * 576;
    u16* wc_lo  = wc_mid + (size_t)192 * 576;

    u16* h1_hi  = (u16*)ws;
    u16* h1_lo  = h1_hi + (size_t)8 * 4096 * 64;
    u16* h1T_hi = h1_lo + (size_t)8 * 4096 * 64;
    u16* h1T_lo = h1T_hi + (size_t)8 * 4096 * 64;
    u16* h2_hi  = (u16*)ws;                          // reuse h1 region (4.19 MB)
    u16* h2_lo  = h2_hi + (size_t)2 * 4096 * 64;
    u16* h2T_hi = h2_lo + (size_t)2 * 4096 * 64;
    u16* h2T_lo = h2T_hi + (size_t)2 * 4096 * 64;
    float* xreg = (float*)(ws + (size_t)4 * 8 * 4096 * 64 * 2);
    float* x1 = xreg;
    float* x2 = xreg;
    // flash1 partials: pO (16 vmaps x 4096 x 64 f32 = 16.78 MB) right after
    // h2 arrays; pml (512 KB) after pO. Both live only during flash1+merge
    // (x2 dead by then; h1 region beyond h2's 4.19 MB dead).
    float* pO  = (float*)(ws + (size_t)4 * 2 * 4096 * 64 * 2);
    float* pml = (float*)(ws + (size_t)4 * 2 * 4096 * 64 * 2 + (size_t)16 * 4096 * 64 * 4);
    float* outp = (float*)d_out;

    hipLaunchKernelGGL(wprep_kernel, dim3(432), dim3(256), 0, stream,
                       w1, w2, w3, wc_hi, wc_mid, wc_lo);
    hipLaunchKernelGGL(timeblock_mfma_kernel, dim3(64, 3), dim3(512), 0, stream,
                       flow, wc_hi, wc_mid, wc_lo, b1, b2, b3, x1);
    // linear 4-head: block 128x128 (8 waves 4x2), grid (64,2), K=192
    hipLaunchKernelGGL(linear_mfma_kernel, dim3(64, 2), dim3(512), 0, stream,
                       x1, Wh, h1_hi, h1_lo, h1T_hi, h1T_lo, 192, 4, 2);
    // flash4: x = 64 row-blocks (graph-row XCD pinning), y = 8 maps
    hipLaunchKernelGGL(flash_mfma_kernel, dim3(64, 8), dim3(256), 0, stream,
                       h1_hi, h1_lo, h1T_hi, h1T_lo, graph, bh, x2, 4, 256,
                       64, 1, 0, (float*)nullptr, (float*)nullptr);
    // linear 1-head: block 256x64 (8 waves 8x1), grid (32,1), K=256
    hipLaunchKernelGGL(linear_mfma_kernel, dim3(32, 1), dim3(512), 0, stream,
                       x2, Wo, h2_hi, h2_lo, h2T_hi, h2T_lo, 256, 1, 1);
    // flash1: 32KB single-buffer kernel; y = map*8+chunk (16); 8 tiles/chunk
    hipLaunchKernelGGL(flash1s_kernel, dim3(64, 16), dim3(256), 0, stream,
                       h2_hi, h2_lo, h2T_hi, h2T_lo, graph,
                       1, 8, 8, pO, pml);
    hipLaunchKernelGGL(merge_kernel, dim3(2048), dim3(256), 0, stream,
                       pO, pml, bo, outp, 8);
}

// Round 18
// 303.402 us; speedup vs baseline: 1.0212x; 1.0212x over previous
//
#include <hip/hip_runtime.h>
#include <math.h>

#define N_NODES 4096

typedef unsigned short u16;
typedef unsigned int u32;

typedef __attribute__((ext_vector_type(8))) short bfrag;   // 8 bf16 = 4 VGPR
typedef __attribute__((ext_vector_type(4))) float f4;

__device__ __forceinline__ u16 f2bf(float x) {
    union { float f; u32 u; } v; v.f = x;
    u32 r = (v.u + 0x7FFFu + ((v.u >> 16) & 1u)) >> 16;   // RNE
    return (u16)r;
}
__device__ __forceinline__ float bf2f(u16 b) {
    union { float f; u32 u; } v; v.u = ((u32)b) << 16; return v.f;
}
__device__ __forceinline__ u32 cvtpk(float a, float b) {   // lo16=bf16(a), hi16=bf16(b)
    u32 r;
    asm("v_cvt_pk_bf16_f32 %0, %1, %2" : "=v"(r) : "v"(a), "v"(b));
    return r;
}
__device__ __forceinline__ float u2f(u32 u) {
    union { u32 u; float f; } v; v.u = u; return v.f;
}
__device__ __forceinline__ float fexp2(float x) {          // 2^x via v_exp_f32
    float r;
    asm("v_exp_f32 %0, %1" : "=v"(r) : "v"(x));
    return r;
}

#define LOG2E 1.4426950408889634f

// ---------------------------------------------------------------------------
// wprep: Wcat[k][col] as bf16 hi/mid/lo in B^T layout [col][576], swizzled.
// ---------------------------------------------------------------------------
__global__ __launch_bounds__(256) void wprep_kernel(
    const float* __restrict__ w1, const float* __restrict__ w2,
    const float* __restrict__ w3,
    u16* __restrict__ w_hi, u16* __restrict__ w_mid, u16* __restrict__ w_lo)
{
    int idx = blockIdx.x * 256 + threadIdx.x;
    if (idx >= 192 * 576) return;
    int col = idx / 576, k = idx % 576;
    int conv = col >> 6, o = col & 63;
    int kk = k / 192, c = k % 192;
    const float* w = (conv == 0) ? w1 : (conv == 1 ? w2 : w3);
    float v = w[(o * 192 + c) * 3 + kk];
    u16 h = f2bf(v);   float r1 = v - bf2f(h);
    u16 m = f2bf(r1);  float r2 = r1 - bf2f(m);
    u16 lo = f2bf(r2);
    int kc = k >> 6, rem = k & 63, j = rem >> 3, e = rem & 7;
    int pos = col * 576 + kc * 64 + ((j ^ (col & 7)) << 3) + e;
    w_hi[pos] = h;
    w_mid[pos] = m;
    w_lo[pos] = lo;
}

// ---------------------------------------------------------------------------
// timeblock_mfma (r6, passing): 3-way-split bf16 MFMA GEMM. grid (64,3).
// ---------------------------------------------------------------------------
__global__ __launch_bounds__(512) void timeblock_mfma_kernel(
    const float* __restrict__ flow,
    const u16* __restrict__ w_hi, const u16* __restrict__ w_mid,
    const u16* __restrict__ w_lo,
    const float* __restrict__ b1, const float* __restrict__ b2,
    const float* __restrict__ b3, float* __restrict__ x1)
{
    __shared__ __align__(16) u16 As[3][128 * 64];
    __shared__ __align__(16) u16 Bs[3][192 * 64];

    const int tid = threadIdx.x;
    const int wv = tid >> 6, l = tid & 63;
    const int ln15 = l & 15, ln16 = l >> 4;
    const int wr = wv >> 1, wc = wv & 1;
    const int nodebase = blockIdx.x * 128;
    const int t = blockIdx.y;

    f4 acc[2][6];
#pragma unroll
    for (int rq = 0; rq < 2; ++rq)
#pragma unroll
        for (int nt = 0; nt < 6; ++nt) {
            acc[rq][nt][0] = 0.f; acc[rq][nt][1] = 0.f;
            acc[rq][nt][2] = 0.f; acc[rq][nt][3] = 0.f;
        }

    for (int kc = 0; kc < 9; ++kc) {
        __syncthreads();

#pragma unroll
        for (int u = tid; u < 1024; u += 512) {
            int r = u >> 3, j = u & 7;
            const float* srcp = flow + (size_t)(nodebase + r) * 960 + t * 192 + kc * 64 + j * 8;
            float4 f0 = *(const float4*)srcp;
            float4 f1 = *(const float4*)(srcp + 4);
            float fv[8] = { f0.x, f0.y, f0.z, f0.w, f1.x, f1.y, f1.z, f1.w };
            union { uint4 q; u16 a[8]; } uh, um, ul;
#pragma unroll
            for (int e = 0; e < 8; ++e) {
                u16 h = f2bf(fv[e]);   float r1 = fv[e] - bf2f(h);
                u16 m = f2bf(r1);      float r2 = r1 - bf2f(m);
                uh.a[e] = h; um.a[e] = m; ul.a[e] = f2bf(r2);
            }
            int pos = r * 64 + ((j ^ (r & 7)) << 3);
            *(uint4*)&As[0][pos] = uh.q;
            *(uint4*)&As[1][pos] = um.q;
            *(uint4*)&As[2][pos] = ul.q;
        }

#pragma unroll
        for (int arr = 0; arr < 3; ++arr) {
            const u16* wsrc = (arr == 0) ? w_hi : (arr == 1 ? w_mid : w_lo);
#pragma unroll
            for (int i = 0; i < 3; ++i) {
                int colg = wv * 24 + i * 8;
                const u16* srcp = wsrc + (size_t)(colg + (l >> 3)) * 576 + kc * 64 + (l & 7) * 8;
                u16* dstp = &Bs[arr][colg * 64];
                __builtin_amdgcn_global_load_lds(
                    (const __attribute__((address_space(1))) u32*)srcp,
                    (__attribute__((address_space(3))) u32*)dstp, 16, 0, 0);
            }
        }

        __syncthreads();

        bfrag af[2][3][2];
#pragma unroll
        for (int rq = 0; rq < 2; ++rq) {
            int arow = wr * 32 + rq * 16 + ln15;
#pragma unroll
            for (int ks = 0; ks < 2; ++ks) {
                int idx = arow * 64 + (((ks * 4 + ln16) ^ (arow & 7)) << 3);
                af[rq][0][ks] = *(const bfrag*)&As[0][idx];
                af[rq][1][ks] = *(const bfrag*)&As[1][idx];
                af[rq][2][ks] = *(const bfrag*)&As[2][idx];
            }
        }

#pragma unroll
        for (int cv = 0; cv < 3; ++cv) {
#pragma unroll
            for (int ntj = 0; ntj < 2; ++ntj) {
                int col = cv * 64 + wc * 32 + ntj * 16 + ln15;
                int nt = cv * 2 + ntj;
#pragma unroll
                for (int ks = 0; ks < 2; ++ks) {
                    int idx = col * 64 + (((ks * 4 + ln16) ^ (col & 7)) << 3);
                    bfrag bh = *(const bfrag*)&Bs[0][idx];
                    bfrag bm = *(const bfrag*)&Bs[1][idx];
                    bfrag bl = *(const bfrag*)&Bs[2][idx];
#pragma unroll
                    for (int rq = 0; rq < 2; ++rq) {
                        f4 a = acc[rq][nt];
                        a = __builtin_amdgcn_mfma_f32_16x16x32_bf16(af[rq][0][ks], bh, a, 0, 0, 0);
                        a = __builtin_amdgcn_mfma_f32_16x16x32_bf16(af[rq][0][ks], bm, a, 0, 0, 0);
                        a = __builtin_amdgcn_mfma_f32_16x16x32_bf16(af[rq][1][ks], bh, a, 0, 0, 0);
                        a = __builtin_amdgcn_mfma_f32_16x16x32_bf16(af[rq][0][ks], bl, a, 0, 0, 0);
                        a = __builtin_amdgcn_mfma_f32_16x16x32_bf16(af[rq][2][ks], bh, a, 0, 0, 0);
                        a = __builtin_amdgcn_mfma_f32_16x16x32_bf16(af[rq][1][ks], bm, a, 0, 0, 0);
                        acc[rq][nt] = a;
                    }
                }
            }
        }
    }

#pragma unroll
    for (int rq = 0; rq < 2; ++rq) {
#pragma unroll
        for (int ntj = 0; ntj < 2; ++ntj) {
            int o = wc * 32 + ntj * 16 + ln15;
            float bb1 = b1[o], bb2 = b2[o], bb3 = b3[o];
#pragma unroll
            for (int rg = 0; rg < 4; ++rg) {
                int node = nodebase + wr * 32 + rq * 16 + ln16 * 4 + rg;
                float c1 = acc[rq][0 * 2 + ntj][rg] + bb1;
                float c2 = acc[rq][1 * 2 + ntj][rg] + bb2;
                float c3 = acc[rq][2 * 2 + ntj][rg] + bb3;
                float sg = 1.0f / (1.0f + __expf(-c2));
                float v = c1 + sg + c3;
                x1[(size_t)node * 192 + t * 64 + o] = v > 0.f ? v : 0.f;
            }
        }
    }
}

// ---------------------------------------------------------------------------
// linear_mfma (r16, passing): 3-way-split bf16 MFMA linear, dual-layout out.
// ---------------------------------------------------------------------------
__global__ __launch_bounds__(512) void linear_mfma_kernel(
    const float* __restrict__ in, const float* __restrict__ W,
    u16* __restrict__ h_hi, u16* __restrict__ h_lo,
    u16* __restrict__ hTb_hi, u16* __restrict__ hTb_lo,
    int C, int H, int nwc)
{
    __shared__ __align__(16) u16 As[3][256 * 64];
    __shared__ __align__(16) u16 Bs[3][128 * 64];

    const int tid = threadIdx.x;
    const int wv = tid >> 6, l = tid & 63;
    const int ln15 = l & 15, ln16 = l >> 4;
    const int wr = wv / nwc, wc = wv - wr * nwc;
    const int rows = 256 / nwc;
    const int ncol = 64 * nwc;
    const int rowbase = blockIdx.x * rows;
    const int colbase = blockIdx.y * ncol;

    f4 acc[2][4];
#pragma unroll
    for (int rq = 0; rq < 2; ++rq)
#pragma unroll
        for (int nt = 0; nt < 4; ++nt) {
            acc[rq][nt][0] = 0.f; acc[rq][nt][1] = 0.f;
            acc[rq][nt][2] = 0.f; acc[rq][nt][3] = 0.f;
        }

    const int nchunks = C >> 6;
    for (int kc = 0; kc < nchunks; ++kc) {
        __syncthreads();

        for (int u = tid; u < rows * 8; u += 512) {
            int r = u >> 3, j = u & 7;
            const float* srcp = in + (size_t)(rowbase + r) * C + kc * 64 + j * 8;
            float4 f0 = *(const float4*)srcp;
            float4 f1 = *(const float4*)(srcp + 4);
            float fv[8] = { f0.x, f0.y, f0.z, f0.w, f1.x, f1.y, f1.z, f1.w };
            union { uint4 q; u16 a[8]; } uh, um, ul;
#pragma unroll
            for (int e = 0; e < 8; ++e) {
                u16 h = f2bf(fv[e]);   float r1 = fv[e] - bf2f(h);
                u16 m = f2bf(r1);      float r2 = r1 - bf2f(m);
                uh.a[e] = h; um.a[e] = m; ul.a[e] = f2bf(r2);
            }
            int pos = r * 64 + ((j ^ (r & 7)) << 3);
            *(uint4*)&As[0][pos] = uh.q;
            *(uint4*)&As[1][pos] = um.q;
            *(uint4*)&As[2][pos] = ul.q;
        }

        for (int u = tid; u < ncol * 8; u += 512) {
            int cdx = u >> 3, j = u & 7;
            const float* srcp = W + (size_t)(colbase + cdx) * C + kc * 64 + j * 8;
            float4 f0 = *(const float4*)srcp;
            float4 f1 = *(const float4*)(srcp + 4);
            float fv[8] = { f0.x, f0.y, f0.z, f0.w, f1.x, f1.y, f1.z, f1.w };
            union { uint4 q; u16 a[8]; } uh, um, ul;
#pragma unroll
            for (int e = 0; e < 8; ++e) {
                u16 h = f2bf(fv[e]);   float r1 = fv[e] - bf2f(h);
                u16 m = f2bf(r1);      float r2 = r1 - bf2f(m);
                uh.a[e] = h; um.a[e] = m; ul.a[e] = f2bf(r2);
            }
            int pos = cdx * 64 + ((j ^ (cdx & 7)) << 3);
            *(uint4*)&Bs[0][pos] = uh.q;
            *(uint4*)&Bs[1][pos] = um.q;
            *(uint4*)&Bs[2][pos] = ul.q;
        }

        __syncthreads();

        bfrag af[2][3][2];
#pragma unroll
        for (int rq = 0; rq < 2; ++rq) {
            int arow = wr * 32 + rq * 16 + ln15;
#pragma unroll
            for (int ks = 0; ks < 2; ++ks) {
                int idx = arow * 64 + (((ks * 4 + ln16) ^ (arow & 7)) << 3);
                af[rq][0][ks] = *(const bfrag*)&As[0][idx];
                af[rq][1][ks] = *(const bfrag*)&As[1][idx];
                af[rq][2][ks] = *(const bfrag*)&As[2][idx];
            }
        }

#pragma unroll
        for (int nt = 0; nt < 4; ++nt) {
            int bcol = wc * 64 + nt * 16 + ln15;
#pragma unroll
            for (int ks = 0; ks < 2; ++ks) {
                int idx = bcol * 64 + (((ks * 4 + ln16) ^ (bcol & 7)) << 3);
                bfrag bh = *(const bfrag*)&Bs[0][idx];
                bfrag bm = *(const bfrag*)&Bs[1][idx];
                bfrag bl = *(const bfrag*)&Bs[2][idx];
#pragma unroll
                for (int rq = 0; rq < 2; ++rq) {
                    f4 a = acc[rq][nt];
                    a = __builtin_amdgcn_mfma_f32_16x16x32_bf16(af[rq][0][ks], bh, a, 0, 0, 0);
                    a = __builtin_amdgcn_mfma_f32_16x16x32_bf16(af[rq][0][ks], bm, a, 0, 0, 0);
                    a = __builtin_amdgcn_mfma_f32_16x16x32_bf16(af[rq][1][ks], bh, a, 0, 0, 0);
                    a = __builtin_amdgcn_mfma_f32_16x16x32_bf16(af[rq][0][ks], bl, a, 0, 0, 0);
                    a = __builtin_amdgcn_mfma_f32_16x16x32_bf16(af[rq][2][ks], bh, a, 0, 0, 0);
                    a = __builtin_amdgcn_mfma_f32_16x16x32_bf16(af[rq][1][ks], bm, a, 0, 0, 0);
                    acc[rq][nt] = a;
                }
            }
        }
    }

#pragma unroll
    for (int rq = 0; rq < 2; ++rq) {
#pragma unroll
        for (int nt = 0; nt < 4; ++nt) {
            int col = colbase + wc * 64 + nt * 16 + ln15;
            int g = col >> 6, d = col & 63;
            u16 hi4[4], lo4[4];
#pragma unroll
            for (int rg = 0; rg < 4; ++rg) {
                float a = acc[rq][nt][rg];
                u16 h = f2bf(a);
                hi4[rg] = h;
                lo4[rg] = f2bf(a - bf2f(h));
            }
            int row0 = rowbase + wr * 32 + rq * 16 + ln16 * 4;
            int b = row0 >> 12;
            int n0 = row0 & 4095;
            size_t mapb = (size_t)(b * H + g) * (4096 * 64);
#pragma unroll
            for (int rg = 0; rg < 4; ++rg) {
                h_hi[mapb + (size_t)(n0 + rg) * 64 + d] = hi4[rg];
                h_lo[mapb + (size_t)(n0 + rg) * 64 + d] = lo4[rg];
            }
            size_t tb = mapb + (size_t)(n0 >> 6) * 4096;
            ushort4 vh = { hi4[0], hi4[1], hi4[2], hi4[3] };
            ushort4 vl = { lo4[0], lo4[1], lo4[2], lo4[3] };
            *(ushort4*)&hTb_hi[tb + (size_t)d * 64 + (n0 & 63)] = vh;
            *(ushort4*)&hTb_lo[tb + (size_t)d * 64 + (n0 & 63)] = vl;
        }
    }
}

// ---------------------------------------------------------------------------
// flash_mfma (r15, kept): K dbuf + V single, 48 KB LDS, x=rowblock pinning.
// mode 0: out = leaky(O/l + bias). mode 1: dump unnormalized O + (m,l).
// ---------------------------------------------------------------------------
__global__ __launch_bounds__(256) void flash_mfma_kernel(
    const u16* __restrict__ h_hi, const u16* __restrict__ h_lo,
    const u16* __restrict__ hTb_hi, const u16* __restrict__ hTb_lo,
    const float* __restrict__ graph, const float* __restrict__ bias,
    float* __restrict__ out, int H, int rstride,
    int ntiles, int nch, int mode, float* __restrict__ pO, float* __restrict__ pml)
{
    __shared__ __align__(16) u16 Ks[2][2][4096];
    __shared__ __align__(16) u16 Vs[2][4096];

    const int tid = threadIdx.x;
    const int wv = tid >> 6;
    const int l = tid & 63;
    const int ln15 = l & 15, ln16 = l >> 4;
    const int bx = blockIdx.y;
    const int by = bx / nch;
    const int chunk = bx - by * nch;
    const int t0 = chunk * ntiles;
    const int bb = by / H, head = by - bb * H;
    const size_t mapb = (size_t)by * (4096 * 64);
    const int rowbase = blockIdx.x * 64;

    const int arow = rowbase + wv * 16 + ln15;
    bfrag ahi[2], alo[2];
#pragma unroll
    for (int ks = 0; ks < 2; ++ks) {
        ahi[ks] = *(const bfrag*)(h_hi + mapb + (size_t)arow * 64 + ks * 32 + ln16 * 8);
        alo[ks] = *(const bfrag*)(h_lo + mapb + (size_t)arow * 64 + ks * 32 + ln16 * 8);
    }

    const u16* gA = (wv == 0 ? h_hi : wv == 1 ? h_lo : wv == 2 ? hTb_hi : hTb_lo) + mapb;
    const int lrow = l >> 3;
    const int stoff = lrow * 64 + (((l & 7) ^ lrow) << 3);

#define STAGE_K(T, BUF)                                                        \
    if (wv < 2) {                                                              \
        const u16* srcp = gA + (size_t)(T) * 4096 + stoff;                     \
        u16* dstp = &Ks[BUF][wv][0];                                           \
        _Pragma("unroll")                                                      \
        for (int i_ = 0; i_ < 8; ++i_)                                         \
            __builtin_amdgcn_global_load_lds(                                  \
                (const __attribute__((address_space(1))) u32*)(srcp + i_ * 512), \
                (__attribute__((address_space(3))) u32*)(dstp + i_ * 512),     \
                16, 0, 0);                                                     \
    }
#define STAGE_V(T)                                                             \
    if (wv >= 2) {                                                             \
        const u16* srcp = gA + (size_t)(T) * 4096 + stoff;                     \
        u16* dstp = &Vs[wv - 2][0];                                            \
        _Pragma("unroll")                                                      \
        for (int i_ = 0; i_ < 8; ++i_)                                         \
            __builtin_amdgcn_global_load_lds(                                  \
                (const __attribute__((address_space(1))) u32*)(srcp + i_ * 512), \
                (__attribute__((address_space(3))) u32*)(dstp + i_ * 512),     \
                16, 0, 0);                                                     \
    }

    const float* grow = graph + (size_t)(rowbase + wv * 16 + ln15) * 4096 + ln16 * 4;

    float m_ = -3.0e38f, l_ = 0.f;
    f4 acco[4];
#pragma unroll
    for (int i = 0; i < 4; ++i) {
        acco[i][0] = 0.f; acco[i][1] = 0.f; acco[i][2] = 0.f; acco[i][3] = 0.f;
    }

    STAGE_K(t0, 0);
    float4 grC[4], grN[4];
#pragma unroll
    for (int cb = 0; cb < 4; ++cb)
        grC[cb] = *(const float4*)(grow + (size_t)t0 * 64 + cb * 16);

    const int srcA = ln15 + ((((ln16 << 1)) & 3) << 4);
    const int srcB = ln15 + ((((ln16 << 1) + 1) & 3) << 4);
    const bool hi2 = (ln16 & 2) != 0;

    for (int tt = 0; tt < ntiles; ++tt) {
        const int t = t0 + tt;
        const int cur = tt & 1;

        __syncthreads();

        STAGE_V(t);
        if (tt + 1 < ntiles) {
            STAGE_K(t + 1, cur ^ 1);
#pragma unroll
            for (int cb = 0; cb < 4; ++cb)
                grN[cb] = *(const float4*)(grow + (size_t)(t + 1) * 64 + cb * 16);
        }

        __builtin_amdgcn_s_setprio(1);
        f4 accs[4];
#pragma unroll
        for (int cb = 0; cb < 4; ++cb) {
            f4 a; a[0] = 0.f; a[1] = 0.f; a[2] = 0.f; a[3] = 0.f;
#pragma unroll
            for (int ks = 0; ks < 2; ++ks) {
                int c = cb * 16 + ln15;
                int idx = c * 64 + (((ks * 4 + ln16) * 8) ^ ((c & 7) << 3));
                bfrag bhi = *(const bfrag*)&Ks[cur][0][idx];
                bfrag blo = *(const bfrag*)&Ks[cur][1][idx];
                a = __builtin_amdgcn_mfma_f32_16x16x32_bf16(bhi, ahi[ks], a, 0, 0, 0);
                a = __builtin_amdgcn_mfma_f32_16x16x32_bf16(bhi, alo[ks], a, 0, 0, 0);
                a = __builtin_amdgcn_mfma_f32_16x16x32_bf16(blo, ahi[ks], a, 0, 0, 0);
            }
            accs[cb] = a;
        }
        __builtin_amdgcn_s_setprio(0);

        float p[4][4];
#pragma unroll
        for (int cb = 0; cb < 4; ++cb) {
            p[cb][0] = accs[cb][0] + fmaf(grC[cb].x, 1e16f, -1e16f);
            p[cb][1] = accs[cb][1] + fmaf(grC[cb].y, 1e16f, -1e16f);
            p[cb][2] = accs[cb][2] + fmaf(grC[cb].z, 1e16f, -1e16f);
            p[cb][3] = accs[cb][3] + fmaf(grC[cb].w, 1e16f, -1e16f);
        }

        float tm = fmaxf(fmaxf(p[0][0], p[0][1]), fmaxf(p[0][2], p[0][3]));
#pragma unroll
        for (int cb = 1; cb < 4; ++cb)
            tm = fmaxf(tm, fmaxf(fmaxf(p[cb][0], p[cb][1]), fmaxf(p[cb][2], p[cb][3])));
        tm = fmaxf(tm, __shfl_xor(tm, 16));
        tm = fmaxf(tm, __shfl_xor(tm, 32));

        const bool anyup = __any(tm > m_);
        float mn, corr;
        if (anyup) {
            mn = fmaxf(m_, tm);
            corr = fexp2((m_ - mn) * LOG2E);
        } else {
            mn = m_;
            corr = 1.0f;
        }
        const float c0 = -mn * LOG2E;

        float rs = 0.f;
#pragma unroll
        for (int cb = 0; cb < 4; ++cb) {
            p[cb][0] = fexp2(fmaf(p[cb][0], LOG2E, c0));
            p[cb][1] = fexp2(fmaf(p[cb][1], LOG2E, c0));
            p[cb][2] = fexp2(fmaf(p[cb][2], LOG2E, c0));
            p[cb][3] = fexp2(fmaf(p[cb][3], LOG2E, c0));
            rs += (p[cb][0] + p[cb][1]) + (p[cb][2] + p[cb][3]);
        }
        rs += __shfl_xor(rs, 16);
        rs += __shfl_xor(rs, 32);
        l_ = l_ * corr + rs;
        m_ = mn;

        if (anyup) {
            float corr4[4];
#pragma unroll
            for (int rg = 0; rg < 4; ++rg)
                corr4[rg] = __shfl(corr, ln16 * 4 + rg);
#pragma unroll
            for (int nb = 0; nb < 4; ++nb) {
                acco[nb][0] *= corr4[0]; acco[nb][1] *= corr4[1];
                acco[nb][2] *= corr4[2]; acco[nb][3] *= corr4[3];
            }
        }

        u32 Uh[4][2], Ul[4][2];
#pragma unroll
        for (int cb = 0; cb < 4; ++cb) {
            u32 uh0 = cvtpk(p[cb][0], p[cb][1]);
            u32 uh1 = cvtpk(p[cb][2], p[cb][3]);
            float h0 = u2f(uh0 << 16), h1 = u2f(uh0 & 0xffff0000u);
            float h2 = u2f(uh1 << 16), h3 = u2f(uh1 & 0xffff0000u);
            Uh[cb][0] = uh0; Uh[cb][1] = uh1;
            Ul[cb][0] = cvtpk(p[cb][0] - h0, p[cb][1] - h1);
            Ul[cb][1] = cvtpk(p[cb][2] - h2, p[cb][3] - h3);
        }

        bfrag pfh[2], pfl[2];
#pragma unroll
        for (int ks = 0; ks < 2; ++ks) {
            u32 w0a = (u32)__shfl((int)Uh[2 * ks + 0][0], srcA);
            u32 w0b = (u32)__shfl((int)Uh[2 * ks + 1][0], srcA);
            u32 w1a = (u32)__shfl((int)Uh[2 * ks + 0][1], srcA);
            u32 w1b = (u32)__shfl((int)Uh[2 * ks + 1][1], srcA);
            u32 w2a = (u32)__shfl((int)Uh[2 * ks + 0][0], srcB);
            u32 w2b = (u32)__shfl((int)Uh[2 * ks + 1][0], srcB);
            u32 w3a = (u32)__shfl((int)Uh[2 * ks + 0][1], srcB);
            u32 w3b = (u32)__shfl((int)Uh[2 * ks + 1][1], srcB);
            union { uint4 q; bfrag f; } ch;
            ch.q.x = hi2 ? w0b : w0a; ch.q.y = hi2 ? w1b : w1a;
            ch.q.z = hi2 ? w2b : w2a; ch.q.w = hi2 ? w3b : w3a;
            pfh[ks] = ch.f;

            u32 v0a = (u32)__shfl((int)Ul[2 * ks + 0][0], srcA);
            u32 v0b = (u32)__shfl((int)Ul[2 * ks + 1][0], srcA);
            u32 v1a = (u32)__shfl((int)Ul[2 * ks + 0][1], srcA);
            u32 v1b = (u32)__shfl((int)Ul[2 * ks + 1][1], srcA);
            u32 v2a = (u32)__shfl((int)Ul[2 * ks + 0][0], srcB);
            u32 v2b = (u32)__shfl((int)Ul[2 * ks + 1][0], srcB);
            u32 v3a = (u32)__shfl((int)Ul[2 * ks + 0][1], srcB);
            u32 v3b = (u32)__shfl((int)Ul[2 * ks + 1][1], srcB);
            union { uint4 q; bfrag f; } cl;
            cl.q.x = hi2 ? v0b : v0a; cl.q.y = hi2 ? v1b : v1a;
            cl.q.z = hi2 ? v2b : v2a; cl.q.w = hi2 ? v3b : v3a;
            pfl[ks] = cl.f;
        }

        __syncthreads();   // publish V(t)

        __builtin_amdgcn_s_setprio(1);
#pragma unroll
        for (int nb = 0; nb < 4; ++nb) {
#pragma unroll
            for (int ks = 0; ks < 2; ++ks) {
                int nr = nb * 16 + ln15;
                int idx = nr * 64 + (((ks * 4 + ln16) * 8) ^ ((nr & 7) << 3));
                bfrag vhi = *(const bfrag*)&Vs[0][idx];
                bfrag vlo = *(const bfrag*)&Vs[1][idx];
                acco[nb] = __builtin_amdgcn_mfma_f32_16x16x32_bf16(pfh[ks], vhi, acco[nb], 0, 0, 0);
                acco[nb] = __builtin_amdgcn_mfma_f32_16x16x32_bf16(pfh[ks], vlo, acco[nb], 0, 0, 0);
                acco[nb] = __builtin_amdgcn_mfma_f32_16x16x32_bf16(pfl[ks], vhi, acco[nb], 0, 0, 0);
            }
        }
        __builtin_amdgcn_s_setprio(0);

        if (tt + 1 < ntiles) {
#pragma unroll
            for (int cb = 0; cb < 4; ++cb)
                grC[cb] = grN[cb];
        }
    }
#undef STAGE_K
#undef STAGE_V

    if (mode == 0) {
        float l4[4];
#pragma unroll
        for (int rg = 0; rg < 4; ++rg)
            l4[rg] = __shfl(l_, ln16 * 4 + rg);

        const float* bv = bias + head * 64;
#pragma unroll
        for (int rg = 0; rg < 4; ++rg) {
            int row = rowbase + wv * 16 + ln16 * 4 + rg;
            float inv = 1.0f / l4[rg];
#pragma unroll
            for (int nb = 0; nb < 4; ++nb) {
                float v = acco[nb][rg] * inv + bv[nb * 16 + ln15];
                v = v > 0.f ? v : 0.01f * v;
                out[(size_t)(bb * N_NODES + row) * rstride + head * 64 + nb * 16 + ln15] = v;
            }
        }
    } else {
        int row = rowbase + wv * 16 + ln15;
        if (ln16 == 0) {
            size_t mi = (((size_t)(by * nch + chunk)) * 4096 + row) * 2;
            pml[mi] = m_;
            pml[mi + 1] = l_;
        }
#pragma unroll
        for (int rg = 0; rg < 4; ++rg) {
            int row2 = rowbase + wv * 16 + ln16 * 4 + rg;
            size_t ob = (((size_t)(by * nch + chunk)) * 4096 + row2) * 64;
#pragma unroll
            for (int nb = 0; nb < 4; ++nb)
                pO[ob + nb * 16 + ln15] = acco[nb][rg];
        }
    }
}

// ---------------------------------------------------------------------------
// merge: combine 4 column-chunk partials -> out = leaky(num/den + bias)
// ---------------------------------------------------------------------------
__global__ __launch_bounds__(256) void merge_kernel(
    const float* __restrict__ pO, const float* __restrict__ pml,
    const float* __restrict__ bias, float* __restrict__ out)
{
    int idx = blockIdx.x * 256 + threadIdx.x;   // 2*4096*64 total
    int feat = idx & 63;
    int row = (idx >> 6) & 4095;
    int map = idx >> 18;

    float mv[4], lv[4];
    float M = -3.0e38f;
#pragma unroll
    for (int c = 0; c < 4; ++c) {
        size_t mi = (((size_t)map * 4 + c) * 4096 + row) * 2;
        mv[c] = pml[mi];
        lv[c] = pml[mi + 1];
        M = fmaxf(M, mv[c]);
    }
    float den = 0.f, num = 0.f;
#pragma unroll
    for (int c = 0; c < 4; ++c) {
        float e = __expf(mv[c] - M);
        den += e * lv[c];
        num += e * pO[(((size_t)map * 4 + c) * 4096 + row) * 64 + feat];
    }
    float v = num / den + bias[feat];
    v = v > 0.f ? v : 0.01f * v;
    out[((size_t)map * 4096 + row) * 64 + feat] = v;
}

// ---------------------------------------------------------------------------
extern "C" void kernel_launch(void* const* d_in, const int* in_sizes, int n_in,
                              void* d_out, int out_size, void* d_ws, size_t ws_size,
                              hipStream_t stream)
{
    const float* flow = (const float*)d_in[0];
    const float* graph = (const float*)d_in[1];
    const float* w1 = (const float*)d_in[2];
    const float* b1 = (const float*)d_in[3];
    const float* w2 = (const float*)d_in[4];
    const float* b2 = (const float*)d_in[5];
    const float* w3 = (const float*)d_in[6];
    const float* b3 = (const float*)d_in[7];
    const float* Wh = (const float*)d_in[8];
    const float* bh = (const float*)d_in[9];
    const float* Wo = (const float*)d_in[10];
    const float* bo = (const float*)d_in[11];

    char* ws = (char*)d_ws;
    u16* wc_hi  = (u16*)ws;                          // aliases h1 region
    u16* wc_mid = wc_hi + (size_t)192 * 576;
    u16* wc_lo  = wc_mid + (size_t)192 * 576;

    u16* h1_hi  = (u16*)ws;
    u16* h1_lo  = h1_hi + (size_t)8 * 4096 * 64;
    u16* h1T_hi = h1_lo + (size_t)8 * 4096 * 64;
    u16* h1T_lo = h1T_hi + (size_t)8 * 4096 * 64;
    u16* h2_hi  = (u16*)ws;                          // reuse h1 region (4.19 MB)
    u16* h2_lo  = h2_hi + (size_t)2 * 4096 * 64;
    u16* h2T_hi = h2_lo + (size_t)2 * 4096 * 64;
    u16* h2T_lo = h2T_hi + (size_t)2 * 4096 * 64;
    float* pml  = (float*)(ws + (size_t)6 * 1024 * 1024);  // dead upper h-region
    float* xreg = (float*)(ws + (size_t)4 * 8 * 4096 * 64 * 2);
    float* x1 = xreg;
    float* x2 = xreg;
    float* pO = xreg;                                 // x2 dead by flash1 time
    float* outp = (float*)d_out;

    hipLaunchKernelGGL(wprep_kernel, dim3(432), dim3(256), 0, stream,
                       w1, w2, w3, wc_hi, wc_mid, wc_lo);
    hipLaunchKernelGGL(timeblock_mfma_kernel, dim3(64, 3), dim3(512), 0, stream,
                       flow, wc_hi, wc_mid, wc_lo, b1, b2, b3, x1);
    // linear 4-head: block 128x128 (8 waves 4x2), grid (64,2), K=192
    hipLaunchKernelGGL(linear_mfma_kernel, dim3(64, 2), dim3(512), 0, stream,
                       x1, Wh, h1_hi, h1_lo, h1T_hi, h1T_lo, 192, 4, 2);
    // flash4: x = 64 row-blocks (graph-row XCD pinning), y = 8 maps
    hipLaunchKernelGGL(flash_mfma_kernel, dim3(64, 8), dim3(256), 0, stream,
                       h1_hi, h1_lo, h1T_hi, h1T_lo, graph, bh, x2, 4, 256,
                       64, 1, 0, (float*)nullptr, (float*)nullptr);
    // linear 1-head: block 256x64 (8 waves 8x1), grid (32,1), K=256
    hipLaunchKernelGGL(linear_mfma_kernel, dim3(32, 1), dim3(512), 0, stream,
                       x2, Wo, h2_hi, h2_lo, h2T_hi, h2T_lo, 256, 1, 1);
    // flash1: x = 64 row-blocks, y = map*4+chunk (8); 16 tiles/chunk; partials
    hipLaunchKernelGGL(flash_mfma_kernel, dim3(64, 8), dim3(256), 0, stream,
                       h2_hi, h2_lo, h2T_hi, h2T_lo, graph, bo, (float*)nullptr, 1, 64,
                       16, 4, 1, pO, pml);
    hipLaunchKernelGGL(merge_kernel, dim3(2048), dim3(256), 0, stream,
                       pO, pml, bo, outp);
}